// Round 1
// baseline (354.469 us; speedup 1.0000x reference)
//
#include <hip/hip_runtime.h>

#define BATCH 64
#define NNODE 512
#define D_IN 768
#define FEA 256
#define HEADS 8
#define M_ROWS (BATCH * NNODE)   // 32768
#define NEG_SLOPE 0.2f

__device__ __forceinline__ float lrelu(float v) { return v >= 0.f ? v : NEG_SLOPE * v; }

// K0: fold attention vectors into Wg: was[h][f] = sum_c Wg[f, h*FEA+c] * att_src[h,c]
__global__ __launch_bounds__(256) void k_att_proj(const float* __restrict__ Wg,
                                                  const float* __restrict__ att_src,
                                                  const float* __restrict__ att_dst,
                                                  float* __restrict__ was,
                                                  float* __restrict__ wad) {
    int h = blockIdx.x;           // 0..7
    int f = threadIdx.x;          // 0..255
    const float* a = (blockIdx.y == 0) ? att_src : att_dst;
    float* o = (blockIdx.y == 0) ? was : wad;
    const float* wrow = Wg + (size_t)f * (HEADS * FEA) + h * FEA;
    const float* av = a + h * FEA;
    float acc = 0.f;
    #pragma unroll 4
    for (int c = 0; c < FEA; c++) acc += wrow[c] * av[c];
    o[h * FEA + f] = acc;
}

// K1: x1 = x @ W1 + b1   (M=32768, K=768, N=256), fp32 tiled
__global__ __launch_bounds__(256) void k_gemm_x1(const float* __restrict__ A,
                                                 const float* __restrict__ Wb,
                                                 const float* __restrict__ bias,
                                                 float* __restrict__ C) {
    const int BM = 64, BN = 64, BK = 16;
    __shared__ float As[BK][BM];   // transposed A tile
    __shared__ float Bs[BK][BN];
    int tid = threadIdx.x;
    int row0 = blockIdx.x * BM, col0 = blockIdx.y * BN;
    int ty = tid >> 4, tx = tid & 15;
    int ar = tid >> 2, ak = (tid & 3) * 4;
    int bk = tid >> 4, bc = (tid & 15) * 4;
    float acc[4][4] = {};
    for (int k0 = 0; k0 < D_IN; k0 += BK) {
        float4 av = *(const float4*)&A[(size_t)(row0 + ar) * D_IN + k0 + ak];
        As[ak + 0][ar] = av.x; As[ak + 1][ar] = av.y;
        As[ak + 2][ar] = av.z; As[ak + 3][ar] = av.w;
        float4 bv = *(const float4*)&Wb[(size_t)(k0 + bk) * FEA + col0 + bc];
        *(float4*)&Bs[bk][bc] = bv;
        __syncthreads();
        #pragma unroll
        for (int kk = 0; kk < BK; kk++) {
            float4 a4 = *(const float4*)&As[kk][ty * 4];
            float4 b4 = *(const float4*)&Bs[kk][tx * 4];
            float aa[4] = {a4.x, a4.y, a4.z, a4.w};
            float bb[4] = {b4.x, b4.y, b4.z, b4.w};
            #pragma unroll
            for (int i = 0; i < 4; i++)
                #pragma unroll
                for (int j = 0; j < 4; j++) acc[i][j] += aa[i] * bb[j];
        }
        __syncthreads();
    }
    float4 bi = *(const float4*)&bias[col0 + tx * 4];
    float bb[4] = {bi.x, bi.y, bi.z, bi.w};
    #pragma unroll
    for (int i = 0; i < 4; i++) {
        float4 o;
        o.x = acc[i][0] + bb[0]; o.y = acc[i][1] + bb[1];
        o.z = acc[i][2] + bb[2]; o.w = acc[i][3] + bb[3];
        *(float4*)&C[(size_t)(row0 + ty * 4 + i) * FEA + col0 + tx * 4] = o;
    }
}

// K2: a_src[b,h,n] = x1[b,n,:] . was[h,:]  (one wave per row)
__global__ __launch_bounds__(256) void k_attn_logits(const float* __restrict__ x1,
                                                     const float* __restrict__ was,
                                                     const float* __restrict__ wad,
                                                     float* __restrict__ a_src,
                                                     float* __restrict__ a_dst) {
    int tid = threadIdx.x;
    int wv = tid >> 6, lane = tid & 63;
    int r = blockIdx.x * 4 + wv;               // 0..32767
    float4 xv = *(const float4*)&x1[(size_t)r * FEA + lane * 4];
    int b = r >> 9, n = r & 511;
    #pragma unroll
    for (int h = 0; h < HEADS; h++) {
        float4 w4 = *(const float4*)&was[h * FEA + lane * 4];
        float p = xv.x * w4.x + xv.y * w4.y + xv.z * w4.z + xv.w * w4.w;
        #pragma unroll
        for (int off = 32; off; off >>= 1) p += __shfl_xor(p, off);
        if (lane == 0) a_src[((size_t)(b * HEADS + h) << 9) + n] = p;
        float4 d4 = *(const float4*)&wad[h * FEA + lane * 4];
        float q = xv.x * d4.x + xv.y * d4.y + xv.z * d4.z + xv.w * d4.w;
        #pragma unroll
        for (int off = 32; off; off >>= 1) q += __shfl_xor(q, off);
        if (lane == 0) a_dst[((size_t)(b * HEADS + h) << 9) + n] = q;
    }
}

// K3: w[b,h,j] = sum_i softmax_j(lrelu(d_i + s_j))  — column sums of softmax
__global__ __launch_bounds__(256) void k_softmax_w(const float* __restrict__ a_src,
                                                   const float* __restrict__ a_dst,
                                                   float* __restrict__ w) {
    __shared__ float s[512], d[512], mrow[512], linv[512];
    __shared__ float red[4];
    int t = threadIdx.x;
    int bh = blockIdx.x;
    const float* sp = a_src + ((size_t)bh << 9);
    const float* dp = a_dst + ((size_t)bh << 9);
    s[t] = sp[t]; s[t + 256] = sp[t + 256];
    d[t] = dp[t]; d[t + 256] = dp[t + 256];
    __syncthreads();
    float mx = fmaxf(s[t], s[t + 256]);
    #pragma unroll
    for (int off = 32; off; off >>= 1) mx = fmaxf(mx, __shfl_xor(mx, off));
    if ((t & 63) == 0) red[t >> 6] = mx;
    __syncthreads();
    float smax = fmaxf(fmaxf(red[0], red[1]), fmaxf(red[2], red[3]));
    #pragma unroll
    for (int ii = 0; ii < 2; ii++) {
        int i = t + ii * 256;
        float di = d[i];
        float mi = lrelu(di + smax);     // true row max (lrelu monotone)
        float l = 0.f;
        for (int j = 0; j < 512; j++) l += __expf(lrelu(di + s[j]) - mi);
        mrow[i] = mi;
        linv[i] = 1.f / l;
    }
    __syncthreads();
    #pragma unroll
    for (int jj = 0; jj < 2; jj++) {
        int j = t + jj * 256;
        float sj = s[j];
        float acc = 0.f;
        for (int i = 0; i < 512; i++) acc += __expf(lrelu(d[i] + sj) - mrow[i]) * linv[i];
        w[((size_t)bh << 9) + j] = acc;
    }
}

// K4: y[b,h,f] = sum_j w[b,h,j] * x1[b,j,f]
__global__ __launch_bounds__(256) void k_aggregate(const float* __restrict__ w,
                                                   const float* __restrict__ x1,
                                                   float* __restrict__ y) {
    __shared__ float wl[512];
    int t = threadIdx.x;
    int b = blockIdx.x, h = blockIdx.y;
    int bh = b * HEADS + h;
    wl[t] = w[((size_t)bh << 9) + t];
    wl[t + 256] = w[((size_t)bh << 9) + t + 256];
    __syncthreads();
    const float* xp = x1 + ((size_t)(b * NNODE)) * FEA + t;
    float acc0 = 0, acc1 = 0, acc2 = 0, acc3 = 0;
    for (int j = 0; j < 512; j += 4) {
        acc0 += wl[j + 0] * xp[(size_t)(j + 0) * FEA];
        acc1 += wl[j + 1] * xp[(size_t)(j + 1) * FEA];
        acc2 += wl[j + 2] * xp[(size_t)(j + 2) * FEA];
        acc3 += wl[j + 3] * xp[(size_t)(j + 3) * FEA];
    }
    y[(size_t)bh * FEA + t] = (acc0 + acc1) + (acc2 + acc3);
}

// K5: out[b,c] = bias_g[c] + (1/(N*H)) * sum_h sum_f y[b,h,f] * Wg[f, h*FEA+c]
__global__ __launch_bounds__(256) void k_final(const float* __restrict__ y,
                                               const float* __restrict__ Wg,
                                               const float* __restrict__ bias_g,
                                               float* __restrict__ out) {
    __shared__ float yl[HEADS][FEA];
    int t = threadIdx.x;
    int b = blockIdx.x;
    #pragma unroll
    for (int h = 0; h < HEADS; h++) yl[h][t] = y[(size_t)(b * HEADS + h) * FEA + t];
    __syncthreads();
    float acc = 0.f;
    for (int f = 0; f < FEA; f++) {
        const float* wrow = Wg + (size_t)f * (HEADS * FEA);
        #pragma unroll
        for (int h = 0; h < HEADS; h++) acc += yl[h][f] * wrow[h * FEA + t];
    }
    out[b * FEA + t] = bias_g[t] + acc * (1.f / (NNODE * HEADS));
}

extern "C" void kernel_launch(void* const* d_in, const int* in_sizes, int n_in,
                              void* d_out, int out_size, void* d_ws, size_t ws_size,
                              hipStream_t stream) {
    const float* x       = (const float*)d_in[0];
    const float* W1      = (const float*)d_in[1];
    const float* b1      = (const float*)d_in[2];
    const float* Wg      = (const float*)d_in[3];
    const float* att_src = (const float*)d_in[4];
    const float* att_dst = (const float*)d_in[5];
    const float* bias_g  = (const float*)d_in[6];
    float* out = (float*)d_out;

    float* ws    = (float*)d_ws;
    float* was   = ws;                              // 2048
    float* wad   = was + HEADS * FEA;               // 2048
    float* x1    = wad + HEADS * FEA;               // 8388608
    float* a_src = x1 + (size_t)M_ROWS * FEA;       // 262144
    float* a_dst = a_src + BATCH * HEADS * NNODE;   // 262144
    float* wsum  = a_dst + BATCH * HEADS * NNODE;   // 262144
    float* y     = wsum + BATCH * HEADS * NNODE;    // 131072

    k_att_proj<<<dim3(HEADS, 2), FEA, 0, stream>>>(Wg, att_src, att_dst, was, wad);
    k_gemm_x1<<<dim3(M_ROWS / 64, FEA / 64), 256, 0, stream>>>(x, W1, b1, x1);
    k_attn_logits<<<M_ROWS / 4, 256, 0, stream>>>(x1, was, wad, a_src, a_dst);
    k_softmax_w<<<BATCH * HEADS, 256, 0, stream>>>(a_src, a_dst, wsum);
    k_aggregate<<<dim3(BATCH, HEADS), 256, 0, stream>>>(wsum, x1, y);
    k_final<<<BATCH, 256, 0, stream>>>(y, Wg, bias_g, out);
}

// Round 3
// 204.671 us; speedup vs baseline: 1.7319x; 1.7319x over previous
//
#include <hip/hip_runtime.h>

#define BATCH 64
#define NNODE 512
#define D_IN 768
#define FEA 256
#define HEADS 8
#define M_ROWS (BATCH * NNODE)   // 32768
#define NEG_SLOPE 0.2f
#define LOG2E 1.4426950408889634f

#define BM 64
#define BK 32
#define LDA_S 40   // LDS row stride in bf16 elems (80B) -> <=2-way bank conflicts on b128

typedef __attribute__((ext_vector_type(4))) float f32x4;
typedef __attribute__((ext_vector_type(8))) short bf16x8;

__device__ __forceinline__ ushort f2bf(float f) {
    union { float f; unsigned u; } v; v.f = f;
    unsigned r = v.u + 0x7fffu + ((v.u >> 16) & 1u);   // RNE
    return (ushort)(r >> 16);
}
__device__ __forceinline__ float lrelu(float v) { return fmaxf(v, NEG_SLOPE * v); }
__device__ __forceinline__ float exp2fast(float v) { return __builtin_amdgcn_exp2f(v); }

// P0: fold attention vectors into Wg: was[h][f] = sum_c Wg[f, h*FEA+c] * att[h,c]
__global__ __launch_bounds__(256) void k_att_proj(const float* __restrict__ Wg,
                                                  const float* __restrict__ att_src,
                                                  const float* __restrict__ att_dst,
                                                  float* __restrict__ was,
                                                  float* __restrict__ wad) {
    int h = blockIdx.x;
    int f = threadIdx.x;
    const float* a = (blockIdx.y == 0) ? att_src : att_dst;
    float* o = (blockIdx.y == 0) ? was : wad;
    const float* wrow = Wg + (size_t)f * (HEADS * FEA) + h * FEA;
    const float* av = a + h * FEA;
    float acc = 0.f;
    #pragma unroll 4
    for (int c = 0; c < FEA; c++) acc += wrow[c] * av[c];
    o[h * FEA + f] = acc;
}

// P1: W1 [k][n] fp32 -> W1p bf16 tiled [kt][n][kk] (kk in 0..31), coalesced GEMM staging
__global__ __launch_bounds__(256) void k_prep_w1t(const float* __restrict__ W1,
                                                  ushort* __restrict__ W1p) {
    __shared__ float T[BK][FEA + 1];
    int kt = blockIdx.x;
    int t = threadIdx.x;
    #pragma unroll
    for (int kk = 0; kk < BK; kk++)
        T[kk][t] = W1[(size_t)(kt * BK + kk) * FEA + t];
    __syncthreads();
    ushort* o = W1p + (size_t)kt * FEA * BK + t * BK;
    #pragma unroll
    for (int kk = 0; kk < BK; kk++) o[kk] = f2bf(T[kk][t]);
}

// K1: x1 = x @ W1 + b1  (M=32768,K=768,N=256) — bf16 MFMA, fp32 accum, fused cast
__global__ __launch_bounds__(256) void k_gemm_x1(const float* __restrict__ A,
                                                 const ushort* __restrict__ W1p,
                                                 const float* __restrict__ bias,
                                                 float* __restrict__ C) {
    __shared__ ushort Asl[BM * LDA_S];     // 64 rows x 40
    __shared__ ushort Bsl[FEA * LDA_S];    // 256 rows x 40
    int t = threadIdx.x;
    int w = t >> 6, l = t & 63;
    int lr = l & 15, lk = l >> 4;
    int row0 = blockIdx.x * BM;

    int arow = t >> 2, akq = (t & 3) * 8;
    const float* aptr = A + (size_t)(row0 + arow) * D_IN + akq;
    const ushort* bptr = W1p + t * BK;
    int rot = (t >> 3) & 3;

    f32x4 ar0 = *(const f32x4*)(aptr);
    f32x4 ar1 = *(const f32x4*)(aptr + 4);
    uint4 br[4];
    {
        const uint4* bp = (const uint4*)bptr;
        br[0] = bp[0]; br[1] = bp[1]; br[2] = bp[2]; br[3] = bp[3];
    }

    f32x4 acc[4][4] = {};

    for (int kt = 0; kt < D_IN / BK; kt++) {
        __syncthreads();
        // A regs -> bf16 -> LDS (b128)
        bf16x8 apk;
        apk[0] = (short)f2bf(ar0.x); apk[1] = (short)f2bf(ar0.y);
        apk[2] = (short)f2bf(ar0.z); apk[3] = (short)f2bf(ar0.w);
        apk[4] = (short)f2bf(ar1.x); apk[5] = (short)f2bf(ar1.y);
        apk[6] = (short)f2bf(ar1.z); apk[7] = (short)f2bf(ar1.w);
        *(bf16x8*)&Asl[arow * LDA_S + akq] = apk;
        // B regs -> LDS, issue-rotated so lanes t and t+8 never hit same bank
        #pragma unroll
        for (int j = 0; j < 4; j++) {
            int jj = (j + rot) & 3;
            *(uint4*)&Bsl[t * LDA_S + jj * 8] = br[jj];
        }
        // prefetch next K-tile into regs (hides HBM latency under MFMA)
        if (kt + 1 < D_IN / BK) {
            ar0 = *(const f32x4*)(aptr + (kt + 1) * BK);
            ar1 = *(const f32x4*)(aptr + (kt + 1) * BK + 4);
            const uint4* bp = (const uint4*)(bptr + (size_t)(kt + 1) * FEA * BK);
            br[0] = bp[0]; br[1] = bp[1]; br[2] = bp[2]; br[3] = bp[3];
        }
        __syncthreads();
        bf16x8 af[4], bfr[4];
        #pragma unroll
        for (int mi = 0; mi < 4; mi++)
            af[mi] = *(bf16x8*)&Asl[(mi * 16 + lr) * LDA_S + lk * 8];
        #pragma unroll
        for (int ni = 0; ni < 4; ni++)
            bfr[ni] = *(bf16x8*)&Bsl[(w * 64 + ni * 16 + lr) * LDA_S + lk * 8];
        #pragma unroll
        for (int mi = 0; mi < 4; mi++)
            #pragma unroll
            for (int ni = 0; ni < 4; ni++)
                acc[mi][ni] = __builtin_amdgcn_mfma_f32_16x16x32_bf16(
                    af[mi], bfr[ni], acc[mi][ni], 0, 0, 0);
    }
    // epilogue: C/D layout col=lane&15, row=(lane>>4)*4+reg  [m89]
    #pragma unroll
    for (int ni = 0; ni < 4; ni++) {
        int col = w * 64 + ni * 16 + lr;
        float bv = bias[col];
        #pragma unroll
        for (int mi = 0; mi < 4; mi++) {
            #pragma unroll
            for (int r = 0; r < 4; r++) {
                int row = row0 + mi * 16 + lk * 4 + r;
                C[(size_t)row * FEA + col] = acc[mi][ni][r] + bv;
            }
        }
    }
}

// K2: a_src[b,h,n] = x1[b,n,:] . was[h,:]  (scaled by log2e for exp2-domain softmax)
__global__ __launch_bounds__(256) void k_attn_logits(const float* __restrict__ x1,
                                                     const float* __restrict__ was,
                                                     const float* __restrict__ wad,
                                                     float* __restrict__ a_src,
                                                     float* __restrict__ a_dst) {
    int tid = threadIdx.x;
    int wv = tid >> 6, lane = tid & 63;
    int r = blockIdx.x * 4 + wv;
    float4 xv = *(const float4*)&x1[(size_t)r * FEA + lane * 4];
    int b = r >> 9, n = r & 511;
    #pragma unroll
    for (int h = 0; h < HEADS; h++) {
        float4 w4 = *(const float4*)&was[h * FEA + lane * 4];
        float p = xv.x * w4.x + xv.y * w4.y + xv.z * w4.z + xv.w * w4.w;
        #pragma unroll
        for (int off = 32; off; off >>= 1) p += __shfl_xor(p, off);
        if (lane == 0) a_src[((size_t)(b * HEADS + h) << 9) + n] = p * LOG2E;
        float4 d4 = *(const float4*)&wad[h * FEA + lane * 4];
        float q = xv.x * d4.x + xv.y * d4.y + xv.z * d4.z + xv.w * d4.w;
        #pragma unroll
        for (int off = 32; off; off >>= 1) q += __shfl_xor(q, off);
        if (lane == 0) a_dst[((size_t)(b * HEADS + h) << 9) + n] = q * LOG2E;
    }
}

// K3: w[b,h,j] = sum_i softmax_j(lrelu(d_i + s_j)) — log2-domain, two-pass
__global__ __launch_bounds__(256) void k_softmax_w(const float* __restrict__ a_src,
                                                   const float* __restrict__ a_dst,
                                                   float* __restrict__ w) {
    __shared__ float s[512], d[512], mrow[512], linv[512];
    __shared__ float red[4];
    int t = threadIdx.x;
    int bh = blockIdx.x;
    const float* sp = a_src + ((size_t)bh << 9);
    const float* dp = a_dst + ((size_t)bh << 9);
    s[t] = sp[t]; s[t + 256] = sp[t + 256];
    d[t] = dp[t]; d[t + 256] = dp[t + 256];
    __syncthreads();
    float mx = fmaxf(s[t], s[t + 256]);
    #pragma unroll
    for (int off = 32; off; off >>= 1) mx = fmaxf(mx, __shfl_xor(mx, off));
    if ((t & 63) == 0) red[t >> 6] = mx;
    __syncthreads();
    float smax = fmaxf(fmaxf(red[0], red[1]), fmaxf(red[2], red[3]));
    #pragma unroll
    for (int ii = 0; ii < 2; ii++) {
        int i = t + ii * 256;
        float di = d[i];
        float mi = lrelu(di + smax);   // true row max (lrelu monotone, scale>0)
        float l = 0.f;
        #pragma unroll 4
        for (int j = 0; j < 512; j++) {
            float v = di + s[j];
            l += exp2fast(fmaxf(v, NEG_SLOPE * v) - mi);
        }
        mrow[i] = mi;
        linv[i] = 1.f / l;
    }
    __syncthreads();
    #pragma unroll
    for (int jj = 0; jj < 2; jj++) {
        int j = t + jj * 256;
        float sj = s[j];
        float acc = 0.f;
        #pragma unroll 4
        for (int i = 0; i < 512; i++) {
            float v = d[i] + sj;
            acc += exp2fast(fmaxf(v, NEG_SLOPE * v) - mrow[i]) * linv[i];
        }
        w[((size_t)bh << 9) + j] = acc;
    }
}

// K4: y_part[b,jc,h,f] = sum_{j in chunk jc} w[b,h,j] * x1[b,j,f]  (x1 read exactly once)
__global__ __launch_bounds__(256) void k_aggregate(const float* __restrict__ w,
                                                   const float* __restrict__ x1,
                                                   float* __restrict__ y_part) {
    __shared__ float wl[HEADS][64];
    int t = threadIdx.x;
    int b = blockIdx.x, jc = blockIdx.y;
    for (int idx = t; idx < 512; idx += 256) {
        int h = idx >> 6, j = idx & 63;
        wl[h][j] = w[((size_t)(b * HEADS + h) << 9) + jc * 64 + j];
    }
    __syncthreads();
    float acc[HEADS] = {};
    const float* xp = x1 + ((size_t)(b * NNODE) + jc * 64) * FEA + t;
    for (int j = 0; j < 64; j++) {
        float v = xp[(size_t)j * FEA];
        #pragma unroll
        for (int h = 0; h < HEADS; h++) acc[h] += wl[h][j] * v;
    }
    #pragma unroll
    for (int h = 0; h < HEADS; h++)
        y_part[(size_t)((b * 8 + jc) * 8 + h) * FEA + t] = acc[h];
}

// K5: y2[b,h,c] = sum_f (sum_jc y_part) * Wg[f, h*FEA+c]
__global__ __launch_bounds__(256) void k_final(const float* __restrict__ y_part,
                                               const float* __restrict__ Wg,
                                               float* __restrict__ y2) {
    __shared__ float yl[FEA];
    int t = threadIdx.x;
    int b = blockIdx.x, h = blockIdx.y;
    float s = 0.f;
    #pragma unroll
    for (int jc = 0; jc < 8; jc++)
        s += y_part[(size_t)((b * 8 + jc) * 8 + h) * FEA + t];
    yl[t] = s;
    __syncthreads();
    float acc = 0.f;
    const float* wp = Wg + h * FEA + t;
    #pragma unroll 4
    for (int f = 0; f < FEA; f++)
        acc += yl[f] * wp[(size_t)f * (HEADS * FEA)];
    y2[(size_t)(b * HEADS + h) * FEA + t] = acc;
}

// K6: out[b,c] = bias_g[c] + mean over heads/nodes
__global__ __launch_bounds__(256) void k_final2(const float* __restrict__ y2,
                                                const float* __restrict__ bias_g,
                                                float* __restrict__ out) {
    int t = threadIdx.x, b = blockIdx.x;
    float acc = 0.f;
    #pragma unroll
    for (int h = 0; h < HEADS; h++) acc += y2[(size_t)(b * HEADS + h) * FEA + t];
    out[b * FEA + t] = bias_g[t] + acc * (1.f / (NNODE * HEADS));
}

extern "C" void kernel_launch(void* const* d_in, const int* in_sizes, int n_in,
                              void* d_out, int out_size, void* d_ws, size_t ws_size,
                              hipStream_t stream) {
    const float* x       = (const float*)d_in[0];
    const float* W1      = (const float*)d_in[1];
    const float* b1      = (const float*)d_in[2];
    const float* Wg      = (const float*)d_in[3];
    const float* att_src = (const float*)d_in[4];
    const float* att_dst = (const float*)d_in[5];
    const float* bias_g  = (const float*)d_in[6];
    float* out = (float*)d_out;

    float* ws     = (float*)d_ws;
    float* was    = ws;                               // 2048
    float* wad    = was + HEADS * FEA;                // 2048
    ushort* W1p   = (ushort*)(wad + HEADS * FEA);     // 196608 u16 = 98304 f
    float* x1     = wad + HEADS * FEA + 98304;        // 8388608
    float* a_src  = x1 + (size_t)M_ROWS * FEA;        // 262144
    float* a_dst  = a_src + BATCH * HEADS * NNODE;    // 262144
    float* wsum   = a_dst + BATCH * HEADS * NNODE;    // 262144
    float* y_part = wsum + BATCH * HEADS * NNODE;     // 1048576
    float* y2     = y_part + 1048576;                 // 131072
    // total ~41.8 MB

    k_att_proj<<<dim3(HEADS, 2), FEA, 0, stream>>>(Wg, att_src, att_dst, was, wad);
    k_prep_w1t<<<D_IN / BK, 256, 0, stream>>>(W1, W1p);
    k_gemm_x1<<<M_ROWS / BM, 256, 0, stream>>>(x, W1p, b1, x1);
    k_attn_logits<<<M_ROWS / 4, 256, 0, stream>>>(x1, was, wad, a_src, a_dst);
    k_softmax_w<<<BATCH * HEADS, 256, 0, stream>>>(a_src, a_dst, wsum);
    k_aggregate<<<dim3(BATCH, 8), 256, 0, stream>>>(wsum, x1, y_part);
    k_final<<<dim3(BATCH, HEADS), 256, 0, stream>>>(y_part, Wg, y2);
    k_final2<<<BATCH, 256, 0, stream>>>(y2, bias_g, out);
}

// Round 4
// 137.845 us; speedup vs baseline: 2.5715x; 1.4848x over previous
//
#include <hip/hip_runtime.h>

#define BATCH 64
#define NNODE 512
#define D_IN 768
#define FEA 256
#define HEADS 8
#define M_ROWS (BATCH * NNODE)   // 32768
#define NEG_SLOPE 0.2f
#define LOG2E 1.4426950408889634f

typedef __attribute__((ext_vector_type(4))) float f32x4;
typedef __attribute__((ext_vector_type(8))) short bf16x8;

__device__ __forceinline__ ushort f2bf(float f) {
    union { float f; unsigned u; } v; v.f = f;
    unsigned r = v.u + 0x7fffu + ((v.u >> 16) & 1u);   // RNE
    return (ushort)(r >> 16);
}
__device__ __forceinline__ float exp2fast(float v) { return __builtin_amdgcn_exp2f(v); }

// P0: fold attention vectors into Wg: was[h][f] = sum_c Wg[f, h*FEA+c] * att[h,c]
__global__ __launch_bounds__(256) void k_att_proj(const float* __restrict__ Wg,
                                                  const float* __restrict__ att_src,
                                                  const float* __restrict__ att_dst,
                                                  float* __restrict__ was,
                                                  float* __restrict__ wad) {
    int h = blockIdx.x;
    int f = threadIdx.x;
    const float* a = (blockIdx.y == 0) ? att_src : att_dst;
    float* o = (blockIdx.y == 0) ? was : wad;
    const float* wrow = Wg + (size_t)f * (HEADS * FEA) + h * FEA;
    const float* av = a + h * FEA;
    float acc = 0.f;
    #pragma unroll 4
    for (int c = 0; c < FEA; c++) acc += wrow[c] * av[c];
    o[h * FEA + f] = acc;
}

// P1: Was1[d,col] = sum_f W1[d,f]*wv[col,f]  (col<8: src head, col>=8: dst head),
// packed bf16 in MFMA B-fragment layout: Bpk[kt*1024 + lane*8 + q] =
//   Was1[kt*32 + (lane>>4)*8 + q][lane&15].  Also c_sd[col] = b1 . wv[col].
__global__ __launch_bounds__(256) void k_prep_was1(const float* __restrict__ W1,
                                                   const float* __restrict__ b1,
                                                   const float* __restrict__ was,
                                                   const float* __restrict__ wad,
                                                   ushort* __restrict__ Bpk,
                                                   float* __restrict__ c_sd) {
    __shared__ float wvl[16 * 260];
    int t = threadIdx.x;
    int kt = blockIdx.x;
    for (int sIdx = t; sIdx < 4096; sIdx += 256) {
        int col = sIdx >> 8, f = sIdx & 255;
        wvl[col * 260 + f] = (col < 8) ? was[col * 256 + f] : wad[(col - 8) * 256 + f];
    }
    __syncthreads();
    int kl = t >> 4, col = t & 15;
    #pragma unroll
    for (int half = 0; half < 2; half++) {
        int kloc = kl + half * 16;
        int k = kt * 32 + kloc;
        const float* wrow = W1 + (size_t)k * 256;
        float acc = 0.f;
        #pragma unroll 4
        for (int f0 = 0; f0 < 256; f0 += 4) {
            float4 a4 = *(const float4*)&wrow[f0];
            float4 v4 = *(const float4*)&wvl[col * 260 + f0];
            acc += a4.x * v4.x + a4.y * v4.y + a4.z * v4.z + a4.w * v4.w;
        }
        Bpk[kt * 1024 + ((kloc >> 3) * 16 + col) * 8 + (kloc & 7)] = f2bf(acc);
    }
    if (kt == 0 && t < 16) {
        float a = 0.f;
        for (int f = 0; f < 256; f++) a += b1[f] * wvl[t * 260 + f];
        c_sd[t] = a;
    }
}

// K1: logits = x @ Was1 + c_sd, scaled by LOG2E.  One MFMA 16x16x32 per wave per k-step;
// A (x fp32) loaded global->reg->bf16, B pre-packed fragments from L2.
__global__ __launch_bounds__(256) void k_logits(const float* __restrict__ x,
                                                const ushort* __restrict__ Bpk,
                                                const float* __restrict__ c_sd,
                                                float* __restrict__ a_src,
                                                float* __restrict__ a_dst) {
    int t = threadIdx.x;
    int w = t >> 6, l = t & 63;
    int lr = l & 15, lk = l >> 4;
    int row0w = blockIdx.x * 64 + w * 16;
    const float* ap = x + (size_t)(row0w + lr) * D_IN + lk * 8;
    const ushort* bp = Bpk + l * 8;

    f32x4 a0 = *(const f32x4*)ap;
    f32x4 a1 = *(const f32x4*)(ap + 4);
    bf16x8 bfr = *(const bf16x8*)bp;
    f32x4 acc = {};

    for (int kt = 0; kt < 24; kt++) {
        f32x4 n0 = a0, n1 = a1;
        bf16x8 nb = bfr;
        if (kt < 23) {
            n0 = *(const f32x4*)(ap + (kt + 1) * 32);
            n1 = *(const f32x4*)(ap + (kt + 1) * 32 + 4);
            nb = *(const bf16x8*)(bp + (kt + 1) * 1024);
        }
        bf16x8 af;
        af[0] = (short)f2bf(a0.x); af[1] = (short)f2bf(a0.y);
        af[2] = (short)f2bf(a0.z); af[3] = (short)f2bf(a0.w);
        af[4] = (short)f2bf(a1.x); af[5] = (short)f2bf(a1.y);
        af[6] = (short)f2bf(a1.z); af[7] = (short)f2bf(a1.w);
        acc = __builtin_amdgcn_mfma_f32_16x16x32_bf16(af, bfr, acc, 0, 0, 0);
        a0 = n0; a1 = n1; bfr = nb;
    }
    // C/D layout: col = lane&15, row = (lane>>4)*4 + reg
    int col = lr;
    float cadd = c_sd[col];
    float* dst = (col < 8) ? a_src : a_dst;
    int h = col & 7;
    #pragma unroll
    for (int r = 0; r < 4; r++) {
        int rr = row0w + lk * 4 + r;
        int b = rr >> 9, n = rr & 511;
        dst[((size_t)(b * 8 + h) << 9) + n] = (acc[r] + cadd) * LOG2E;
    }
}

// K2: w[bh,j] = sum_i softmax_j(lrelu(d_i + s_j));  s_w[bh] = sum_j w.  (log2 domain)
__global__ __launch_bounds__(512) void k_softmax(const float* __restrict__ a_src,
                                                 const float* __restrict__ a_dst,
                                                 float* __restrict__ wout,
                                                 float* __restrict__ s_w) {
    __shared__ float s[512], dl[512], mrow[512], linv[512];
    __shared__ float red[8], red2[8];
    int t = threadIdx.x;
    int bh = blockIdx.x;
    float sv = a_src[((size_t)bh << 9) + t];
    float dv = a_dst[((size_t)bh << 9) + t];
    s[t] = sv; dl[t] = dv;
    __syncthreads();
    float mx = sv;
    #pragma unroll
    for (int off = 32; off; off >>= 1) mx = fmaxf(mx, __shfl_xor(mx, off));
    if ((t & 63) == 0) red[t >> 6] = mx;
    __syncthreads();
    mx = red[0];
    #pragma unroll
    for (int k = 1; k < 8; k++) mx = fmaxf(mx, red[k]);
    // pass 1: i = t
    float vi = dv + mx;
    float mi = fmaxf(vi, NEG_SLOPE * vi);      // row max (lrelu monotone)
    float L = 0.f;
    for (int j0 = 0; j0 < 512; j0 += 4) {
        float4 s4 = *(const float4*)&s[j0];
        float v0 = dv + s4.x, v1 = dv + s4.y, v2 = dv + s4.z, v3 = dv + s4.w;
        L += exp2fast(fmaxf(v0, NEG_SLOPE * v0) - mi);
        L += exp2fast(fmaxf(v1, NEG_SLOPE * v1) - mi);
        L += exp2fast(fmaxf(v2, NEG_SLOPE * v2) - mi);
        L += exp2fast(fmaxf(v3, NEG_SLOPE * v3) - mi);
    }
    mrow[t] = mi;
    linv[t] = 1.f / L;
    __syncthreads();
    // pass 2: j = t
    float acc = 0.f;
    for (int i0 = 0; i0 < 512; i0 += 4) {
        float4 d4 = *(const float4*)&dl[i0];
        float4 m4 = *(const float4*)&mrow[i0];
        float4 l4 = *(const float4*)&linv[i0];
        float v0 = d4.x + sv, v1 = d4.y + sv, v2 = d4.z + sv, v3 = d4.w + sv;
        acc += exp2fast(fmaxf(v0, NEG_SLOPE * v0) - m4.x) * l4.x;
        acc += exp2fast(fmaxf(v1, NEG_SLOPE * v1) - m4.y) * l4.y;
        acc += exp2fast(fmaxf(v2, NEG_SLOPE * v2) - m4.z) * l4.z;
        acc += exp2fast(fmaxf(v3, NEG_SLOPE * v3) - m4.w) * l4.w;
    }
    wout[((size_t)bh << 9) + t] = acc;
    // s_w reduce
    float ssum = acc;
    #pragma unroll
    for (int off = 32; off; off >>= 1) ssum += __shfl_xor(ssum, off);
    __syncthreads();
    if ((t & 63) == 0) red2[t >> 6] = ssum;
    __syncthreads();
    if (t == 0) {
        float a = 0.f;
        #pragma unroll
        for (int k = 0; k < 8; k++) a += red2[k];
        s_w[bh] = a;
    }
}

// K3: z_part[(b*8+jc)*8+h][d] = sum_{j in chunk} w[b,h,j] * x[b,j,d]
__global__ __launch_bounds__(256) void k_zsum(const float* __restrict__ w,
                                              const float* __restrict__ x,
                                              float* __restrict__ z_part) {
    __shared__ float wl[512];   // [h][64]
    int t = threadIdx.x;
    int b = blockIdx.x, jc = blockIdx.y;
    {
        int idx = t;
        wl[idx] = w[((size_t)(b * 8 + (idx >> 6)) << 9) + jc * 64 + (idx & 63)];
        idx = t + 256;
        wl[idx] = w[((size_t)(b * 8 + (idx >> 6)) << 9) + jc * 64 + (idx & 63)];
    }
    __syncthreads();
    float acc[8][3] = {};
    const float* xp = x + ((size_t)(b * 512 + jc * 64)) * D_IN + t;
    for (int j0 = 0; j0 < 64; j0 += 4) {
        float4 wq[8];
        #pragma unroll
        for (int h = 0; h < 8; h++) wq[h] = *(const float4*)&wl[h * 64 + j0];
        #pragma unroll
        for (int jj = 0; jj < 4; jj++) {
            float x0 = xp[(size_t)(j0 + jj) * D_IN];
            float x1 = xp[(size_t)(j0 + jj) * D_IN + 256];
            float x2 = xp[(size_t)(j0 + jj) * D_IN + 512];
            #pragma unroll
            for (int h = 0; h < 8; h++) {
                float wv = (jj == 0) ? wq[h].x : (jj == 1) ? wq[h].y : (jj == 2) ? wq[h].z : wq[h].w;
                acc[h][0] += wv * x0;
                acc[h][1] += wv * x1;
                acc[h][2] += wv * x2;
            }
        }
    }
    #pragma unroll
    for (int h = 0; h < 8; h++) {
        size_t base = ((size_t)((b * 8 + jc) * 8 + h)) * D_IN + t;
        z_part[base] = acc[h][0];
        z_part[base + 256] = acc[h][1];
        z_part[base + 512] = acc[h][2];
    }
}

// K4: y_part[ds][bh][f] = sum_{d in slice} z[bh,d]*W1[d,f]  (+ s_w*b1 on ds==0)
__global__ __launch_bounds__(256) void k_y(const float* __restrict__ z_part,
                                           const float* __restrict__ W1,
                                           const float* __restrict__ b1,
                                           const float* __restrict__ s_w,
                                           float* __restrict__ y_part) {
    __shared__ float zl[8 * 196];
    int t = threadIdx.x;
    int b = blockIdx.x, ds = blockIdx.y;
    for (int sIdx = t; sIdx < 1536; sIdx += 256) {
        int k = sIdx / 192, dd = sIdx - k * 192;
        float v = 0.f;
        #pragma unroll
        for (int jc = 0; jc < 8; jc++)
            v += z_part[((size_t)((b * 8 + jc) * 8 + k)) * D_IN + ds * 192 + dd];
        zl[k * 196 + dd] = v;
    }
    __syncthreads();
    float acc[8] = {};
    for (int dq = 0; dq < 48; dq++) {
        int dbase = ds * 192 + dq * 4;
        float w0 = W1[(size_t)(dbase + 0) * 256 + t];
        float w1 = W1[(size_t)(dbase + 1) * 256 + t];
        float w2 = W1[(size_t)(dbase + 2) * 256 + t];
        float w3 = W1[(size_t)(dbase + 3) * 256 + t];
        #pragma unroll
        for (int k = 0; k < 8; k++) {
            float4 zq = *(const float4*)&zl[k * 196 + dq * 4];
            acc[k] += zq.x * w0 + zq.y * w1 + zq.z * w2 + zq.w * w3;
        }
    }
    #pragma unroll
    for (int k = 0; k < 8; k++) {
        float v = acc[k];
        if (ds == 0) v += s_w[b * 8 + k] * b1[t];
        y_part[((size_t)ds * 512 + b * 8 + k) * 256 + t] = v;
    }
}

// K5: out_part[fs][b][c] = sum_{f in slice} sum_h Y[b,h,f] * Wg[f, h*256+c]
__global__ __launch_bounds__(256) void k_out(const float* __restrict__ y_part,
                                             const float* __restrict__ Wg,
                                             float* __restrict__ out_part) {
    __shared__ float Yl[8 * 68];
    int t = threadIdx.x;
    int b = blockIdx.x, fs = blockIdx.y;
    int f0 = fs * 64;
    for (int sIdx = t; sIdx < 512; sIdx += 256) {
        int h = sIdx >> 6, fl = sIdx & 63;
        float v = 0.f;
        #pragma unroll
        for (int ds = 0; ds < 4; ds++)
            v += y_part[((size_t)ds * 512 + b * 8 + h) * 256 + f0 + fl];
        Yl[h * 68 + fl] = v;
    }
    __syncthreads();
    float acc = 0.f;
    for (int fq = 0; fq < 16; fq++) {
        #pragma unroll
        for (int h = 0; h < 8; h++) {
            float4 yv = *(const float4*)&Yl[h * 68 + fq * 4];
            const float* wp = Wg + (size_t)(f0 + fq * 4) * 2048 + h * 256 + t;
            acc += yv.x * wp[0] + yv.y * wp[2048] + yv.z * wp[4096] + yv.w * wp[6144];
        }
    }
    out_part[(size_t)(fs * 64 + b) * 256 + t] = acc;
}

// K6: out[b,c] = bias_g[c] + (1/4096) * sum_fs out_part
__global__ __launch_bounds__(256) void k_out2(const float* __restrict__ out_part,
                                              const float* __restrict__ bias_g,
                                              float* __restrict__ out) {
    int t = threadIdx.x, b = blockIdx.x;
    float acc = 0.f;
    #pragma unroll
    for (int fs = 0; fs < 4; fs++) acc += out_part[(size_t)(fs * 64 + b) * 256 + t];
    out[b * 256 + t] = bias_g[t] + acc * (1.f / 4096.f);
}

extern "C" void kernel_launch(void* const* d_in, const int* in_sizes, int n_in,
                              void* d_out, int out_size, void* d_ws, size_t ws_size,
                              hipStream_t stream) {
    const float* x       = (const float*)d_in[0];
    const float* W1      = (const float*)d_in[1];
    const float* b1      = (const float*)d_in[2];
    const float* Wg      = (const float*)d_in[3];
    const float* att_src = (const float*)d_in[4];
    const float* att_dst = (const float*)d_in[5];
    const float* bias_g  = (const float*)d_in[6];
    float* out = (float*)d_out;

    float* ws       = (float*)d_ws;
    float* was      = ws;                         // 2048
    float* wad      = ws + 2048;                  // 2048
    float* c_sd     = ws + 4096;                  // 16
    ushort* Bpk     = (ushort*)(ws + 4112);       // 24576 u16 = 12288 f
    float* a_src    = ws + 16400;                 // 262144
    float* a_dst    = ws + 278544;                // 262144
    float* wsum     = ws + 540688;                // 262144
    float* s_w      = ws + 802832;                // 512
    float* z_part   = ws + 803344;                // 3145728
    float* y_part   = ws + 3949072;               // 524288
    float* out_part = ws + 4473360;               // 65536  -> total 4538896 f = 18.2 MB

    k_att_proj<<<dim3(HEADS, 2), 256, 0, stream>>>(Wg, att_src, att_dst, was, wad);
    k_prep_was1<<<24, 256, 0, stream>>>(W1, b1, was, wad, Bpk, c_sd);
    k_logits<<<M_ROWS / 64, 256, 0, stream>>>(x, Bpk, c_sd, a_src, a_dst);
    k_softmax<<<BATCH * HEADS, 512, 0, stream>>>(a_src, a_dst, wsum, s_w);
    k_zsum<<<dim3(BATCH, 8), 256, 0, stream>>>(wsum, x, z_part);
    k_y<<<dim3(BATCH, 4), 256, 0, stream>>>(z_part, W1, b1, s_w, y_part);
    k_out<<<dim3(BATCH, 4), 256, 0, stream>>>(y_part, Wg, out_part);
    k_out2<<<BATCH, 256, 0, stream>>>(out_part, bias_g, out);
}

// Round 5
// 104.339 us; speedup vs baseline: 3.3973x; 1.3211x over previous
//
#include <hip/hip_runtime.h>

#define BATCH 64
#define NNODE 512
#define D_IN 768
#define FEA 256
#define HEADS 8
#define M_ROWS (BATCH * NNODE)   // 32768
#define NEG_SLOPE 0.2f
#define LOG2E 1.4426950408889634f

typedef __attribute__((ext_vector_type(4))) float f32x4;
typedef __attribute__((ext_vector_type(8))) short bf16x8;

__device__ __forceinline__ ushort f2bf(float f) {
    union { float f; unsigned u; } v; v.f = f;
    unsigned r = v.u + 0x7fffu + ((v.u >> 16) & 1u);   // RNE
    return (ushort)(r >> 16);
}
__device__ __forceinline__ float exp2fast(float v) { return __builtin_amdgcn_exp2f(v); }

// P0: fold attention vectors into Wg: was[h][f] = sum_c Wg[f, h*FEA+c] * att[h,c]
__global__ __launch_bounds__(256) void k_att_proj(const float* __restrict__ Wg,
                                                  const float* __restrict__ att_src,
                                                  const float* __restrict__ att_dst,
                                                  float* __restrict__ was,
                                                  float* __restrict__ wad) {
    int h = blockIdx.x;
    int f = threadIdx.x;
    const float* a = (blockIdx.y == 0) ? att_src : att_dst;
    float* o = (blockIdx.y == 0) ? was : wad;
    const float* wrow = Wg + (size_t)f * (HEADS * FEA) + h * FEA;
    const float* av = a + h * FEA;
    float acc = 0.f;
    #pragma unroll 4
    for (int c = 0; c < FEA; c++) acc += wrow[c] * av[c];
    o[h * FEA + f] = acc;
}

// P1: Was1[d,col] = sum_f W1[d,f]*wv[col,f] packed bf16 in MFMA B-frag layout; c_sd = b1.wv
__global__ __launch_bounds__(256) void k_prep_was1(const float* __restrict__ W1,
                                                   const float* __restrict__ b1,
                                                   const float* __restrict__ was,
                                                   const float* __restrict__ wad,
                                                   ushort* __restrict__ Bpk,
                                                   float* __restrict__ c_sd) {
    __shared__ float wvl[16 * 260];
    int t = threadIdx.x;
    int kt = blockIdx.x;
    for (int sIdx = t; sIdx < 4096; sIdx += 256) {
        int col = sIdx >> 8, f = sIdx & 255;
        wvl[col * 260 + f] = (col < 8) ? was[col * 256 + f] : wad[(col - 8) * 256 + f];
    }
    __syncthreads();
    int kl = t >> 4, col = t & 15;
    #pragma unroll
    for (int half = 0; half < 2; half++) {
        int kloc = kl + half * 16;
        int k = kt * 32 + kloc;
        const float* wrow = W1 + (size_t)k * 256;
        float acc = 0.f;
        #pragma unroll 4
        for (int f0 = 0; f0 < 256; f0 += 4) {
            float4 a4 = *(const float4*)&wrow[f0];
            float4 v4 = *(const float4*)&wvl[col * 260 + f0];
            acc += a4.x * v4.x + a4.y * v4.y + a4.z * v4.z + a4.w * v4.w;
        }
        Bpk[kt * 1024 + ((kloc >> 3) * 16 + col) * 8 + (kloc & 7)] = f2bf(acc);
    }
    if (kt == 0 && t < 16) {
        float a = 0.f;
        for (int f = 0; f < 256; f++) a += b1[f] * wvl[t * 260 + f];
        c_sd[t] = a;
    }
}

// K1: logits = (x @ Was1 + c_sd) * LOG2E via one MFMA column per wave
__global__ __launch_bounds__(256) void k_logits(const float* __restrict__ x,
                                                const ushort* __restrict__ Bpk,
                                                const float* __restrict__ c_sd,
                                                float* __restrict__ a_src,
                                                float* __restrict__ a_dst) {
    int t = threadIdx.x;
    int w = t >> 6, l = t & 63;
    int lr = l & 15, lk = l >> 4;
    int row0w = blockIdx.x * 64 + w * 16;
    const float* ap = x + (size_t)(row0w + lr) * D_IN + lk * 8;
    const ushort* bp = Bpk + l * 8;

    f32x4 a0 = *(const f32x4*)ap;
    f32x4 a1 = *(const f32x4*)(ap + 4);
    bf16x8 bfr = *(const bf16x8*)bp;
    f32x4 acc = {};

    for (int kt = 0; kt < 24; kt++) {
        f32x4 n0 = a0, n1 = a1;
        bf16x8 nb = bfr;
        if (kt < 23) {
            n0 = *(const f32x4*)(ap + (kt + 1) * 32);
            n1 = *(const f32x4*)(ap + (kt + 1) * 32 + 4);
            nb = *(const bf16x8*)(bp + (kt + 1) * 1024);
        }
        bf16x8 af;
        af[0] = (short)f2bf(a0.x); af[1] = (short)f2bf(a0.y);
        af[2] = (short)f2bf(a0.z); af[3] = (short)f2bf(a0.w);
        af[4] = (short)f2bf(a1.x); af[5] = (short)f2bf(a1.y);
        af[6] = (short)f2bf(a1.z); af[7] = (short)f2bf(a1.w);
        acc = __builtin_amdgcn_mfma_f32_16x16x32_bf16(af, bfr, acc, 0, 0, 0);
        a0 = n0; a1 = n1; bfr = nb;
    }
    int col = lr;
    float cadd = c_sd[col];
    float* dst = (col < 8) ? a_src : a_dst;
    int h = col & 7;
    #pragma unroll
    for (int r = 0; r < 4; r++) {
        int rr = row0w + lk * 4 + r;
        int b = rr >> 9, n = rr & 511;
        dst[((size_t)(b * 8 + h) << 9) + n] = (acc[r] + cadd) * LOG2E;
    }
}

// K2: O(N log N) softmax column-sums via sort + prefix sums.
// lrelu splits in two linear pieces; sorted s/d make pos/neg sets suffix/prefix.
__global__ __launch_bounds__(512) void k_softmax(const float* __restrict__ a_src,
                                                 const float* __restrict__ a_dst,
                                                 float* __restrict__ wout,
                                                 float* __restrict__ s_w) {
    __shared__ float s_srt[512], d_srt[512];
    __shared__ float E1[512], E2[512], PA[512], PB[512];
    __shared__ float red[8];
    int t = threadIdx.x;
    int bh = blockIdx.x;
    float sv = a_src[((size_t)bh << 9) + t];
    float dv = a_dst[((size_t)bh << 9) + t];
    s_srt[t] = sv; d_srt[t] = dv;
    __syncthreads();
    // smax
    float mx = sv;
    #pragma unroll
    for (int off = 32; off; off >>= 1) mx = fmaxf(mx, __shfl_xor(mx, off));
    if ((t & 63) == 0) red[t >> 6] = mx;
    __syncthreads();
    mx = red[0];
    #pragma unroll
    for (int k = 1; k < 8; k++) mx = fmaxf(mx, red[k]);
    __syncthreads();
    // bitonic sort (ascending) both arrays, shared syncs
    for (int k = 2; k <= 512; k <<= 1) {
        for (int j = k >> 1; j > 0; j >>= 1) {
            int ixj = t ^ j;
            if (ixj > t) {
                bool up = ((t & k) == 0);
                float a = s_srt[t], b = s_srt[ixj];
                if ((a > b) == up) { s_srt[t] = b; s_srt[ixj] = a; }
                float c = d_srt[t], e = d_srt[ixj];
                if ((c > e) == up) { d_srt[t] = e; d_srt[ixj] = c; }
            }
            __syncthreads();
        }
    }
    // prefix sums of e1 = 2^(s-mx), e2 = 2^(0.2(s-mx)) over sorted s
    {
        float ssv = s_srt[t];
        E1[t] = exp2fast(ssv - mx);
        E2[t] = exp2fast(0.2f * (ssv - mx));
    }
    __syncthreads();
    for (int off = 1; off < 512; off <<= 1) {
        float a1 = (t >= off) ? E1[t - off] : 0.f;
        float a2 = (t >= off) ? E2[t - off] : 0.f;
        __syncthreads();
        E1[t] += a1; E2[t] += a2;
        __syncthreads();
    }
    float E1tot = E1[511], E2tot = E2[511];
    (void)E2tot;
    // per sorted-row i: L_i, then A'_i, B'_i
    float dsv = d_srt[t];
    float v = dsv + mx;
    float mi = fmaxf(v, NEG_SLOPE * v);
    float key = -dsv;
    int lo = 0, hi = 512;   // lower_bound over s_srt
    #pragma unroll
    for (int it = 0; it < 9; it++) {
        if (lo < hi) {
            int mid = (lo + hi) >> 1;
            if (s_srt[mid] < key) lo = mid + 1; else hi = mid;
        }
    }
    float e1pre = lo ? E1[lo - 1] : 0.f;
    float e2pre = lo ? E2[lo - 1] : 0.f;
    float ga = exp2fast(v - mi);           // <=1
    float gb = exp2fast(0.2f * v - mi);    // <=1
    float L = ga * (E1tot - e1pre) + gb * e2pre;
    float linv = 1.f / L;
    PA[t] = ga * linv;
    PB[t] = gb * linv;
    __syncthreads();
    for (int off = 1; off < 512; off <<= 1) {
        float a1 = (t >= off) ? PA[t - off] : 0.f;
        float a2 = (t >= off) ? PB[t - off] : 0.f;
        __syncthreads();
        PA[t] += a1; PB[t] += a2;
        __syncthreads();
    }
    float PAtot = PA[511], PBtot = PB[511];
    (void)PBtot;
    // per original column j (= t): w_j
    float key2 = -sv;
    int lo2 = 0, hi2 = 512;   // lower_bound over d_srt
    #pragma unroll
    for (int it = 0; it < 9; it++) {
        if (lo2 < hi2) {
            int mid = (lo2 + hi2) >> 1;
            if (d_srt[mid] < key2) lo2 = mid + 1; else hi2 = mid;
        }
    }
    float papre = lo2 ? PA[lo2 - 1] : 0.f;
    float pbpre = lo2 ? PB[lo2 - 1] : 0.f;
    float e1j = exp2fast(sv - mx);
    float e2j = exp2fast(0.2f * (sv - mx));
    float wj = e1j * (PAtot - papre) + e2j * pbpre;
    wout[((size_t)bh << 9) + t] = wj;
    // s_w reduce
    float ssum = wj;
    #pragma unroll
    for (int off = 32; off; off >>= 1) ssum += __shfl_xor(ssum, off);
    __syncthreads();
    if ((t & 63) == 0) red[t >> 6] = ssum;
    __syncthreads();
    if (t == 0) {
        float a = 0.f;
        #pragma unroll
        for (int k = 0; k < 8; k++) a += red[k];
        s_w[bh] = a;
    }
}

// K3: z_part[(b*8+jc)*8+h][d] = sum_{j in chunk} w[b,h,j] * x[b,j,d]
__global__ __launch_bounds__(256) void k_zsum(const float* __restrict__ w,
                                              const float* __restrict__ x,
                                              float* __restrict__ z_part) {
    __shared__ float wl[512];   // [h][64]
    int t = threadIdx.x;
    int b = blockIdx.x, jc = blockIdx.y;
    {
        int idx = t;
        wl[idx] = w[((size_t)(b * 8 + (idx >> 6)) << 9) + jc * 64 + (idx & 63)];
        idx = t + 256;
        wl[idx] = w[((size_t)(b * 8 + (idx >> 6)) << 9) + jc * 64 + (idx & 63)];
    }
    __syncthreads();
    float acc[8][3] = {};
    const float* xp = x + ((size_t)(b * 512 + jc * 64)) * D_IN + t;
    for (int j0 = 0; j0 < 64; j0 += 4) {
        float4 wq[8];
        #pragma unroll
        for (int h = 0; h < 8; h++) wq[h] = *(const float4*)&wl[h * 64 + j0];
        #pragma unroll
        for (int jj = 0; jj < 4; jj++) {
            float x0 = xp[(size_t)(j0 + jj) * D_IN];
            float x1 = xp[(size_t)(j0 + jj) * D_IN + 256];
            float x2 = xp[(size_t)(j0 + jj) * D_IN + 512];
            #pragma unroll
            for (int h = 0; h < 8; h++) {
                float wv = (jj == 0) ? wq[h].x : (jj == 1) ? wq[h].y : (jj == 2) ? wq[h].z : wq[h].w;
                acc[h][0] += wv * x0;
                acc[h][1] += wv * x1;
                acc[h][2] += wv * x2;
            }
        }
    }
    #pragma unroll
    for (int h = 0; h < 8; h++) {
        size_t base = ((size_t)((b * 8 + jc) * 8 + h)) * D_IN + t;
        z_part[base] = acc[h][0];
        z_part[base + 256] = acc[h][1];
        z_part[base + 512] = acc[h][2];
    }
}

// K4: y_part[ds][bh][f] = sum_{d in slice} z[bh,d]*W1[d,f]  (+ s_w*b1 on ds==0)
__global__ __launch_bounds__(256) void k_y(const float* __restrict__ z_part,
                                           const float* __restrict__ W1,
                                           const float* __restrict__ b1,
                                           const float* __restrict__ s_w,
                                           float* __restrict__ y_part) {
    __shared__ float zl[8 * 196];
    int t = threadIdx.x;
    int b = blockIdx.x, ds = blockIdx.y;
    for (int sIdx = t; sIdx < 1536; sIdx += 256) {
        int k = sIdx / 192, dd = sIdx - k * 192;
        float v = 0.f;
        #pragma unroll
        for (int jc = 0; jc < 8; jc++)
            v += z_part[((size_t)((b * 8 + jc) * 8 + k)) * D_IN + ds * 192 + dd];
        zl[k * 196 + dd] = v;
    }
    __syncthreads();
    float acc[8] = {};
    for (int dq = 0; dq < 48; dq++) {
        int dbase = ds * 192 + dq * 4;
        float w0 = W1[(size_t)(dbase + 0) * 256 + t];
        float w1 = W1[(size_t)(dbase + 1) * 256 + t];
        float w2 = W1[(size_t)(dbase + 2) * 256 + t];
        float w3 = W1[(size_t)(dbase + 3) * 256 + t];
        #pragma unroll
        for (int k = 0; k < 8; k++) {
            float4 zq = *(const float4*)&zl[k * 196 + dq * 4];
            acc[k] += zq.x * w0 + zq.y * w1 + zq.z * w2 + zq.w * w3;
        }
    }
    #pragma unroll
    for (int k = 0; k < 8; k++) {
        float v = acc[k];
        if (ds == 0) v += s_w[b * 8 + k] * b1[t];
        y_part[((size_t)ds * 512 + b * 8 + k) * 256 + t] = v;
    }
}

// K5: out_part[(h*4+fs)][b][c] = sum_{f in fs-slice} Y[b,h,f]*Wg[f, h*256+c]
// Wg read ~8MB total (vs 128MB logical before); Y staged in LDS
__global__ __launch_bounds__(256) void k_out(const float* __restrict__ y_part,
                                             const float* __restrict__ Wg,
                                             float* __restrict__ out_part) {
    __shared__ float Yl[64][16];   // [fl][bl]
    int t = threadIdx.x;
    int h = blockIdx.x, fs = blockIdx.y, bq = blockIdx.z;
    int f0 = fs * 64, b0 = bq * 16;
    for (int sIdx = t; sIdx < 1024; sIdx += 256) {
        int bl = sIdx >> 6, fl = sIdx & 63;
        float v = 0.f;
        #pragma unroll
        for (int ds = 0; ds < 4; ds++)
            v += y_part[((size_t)(ds * 512) + (b0 + bl) * 8 + h) * 256 + f0 + fl];
        Yl[fl][bl] = v;
    }
    __syncthreads();
    float acc[16] = {};
    for (int fl = 0; fl < 64; fl++) {
        float wv = Wg[(size_t)(f0 + fl) * 2048 + h * 256 + t];
        #pragma unroll
        for (int bl = 0; bl < 16; bl++) acc[bl] += Yl[fl][bl] * wv;
    }
    #pragma unroll
    for (int bl = 0; bl < 16; bl++)
        out_part[((size_t)(h * 4 + fs) * 64 + b0 + bl) * 256 + t] = acc[bl];
}

// K6: out[b,c] = bias_g[c] + (1/4096) * sum_k out_part[k][b][c]
__global__ __launch_bounds__(256) void k_out2(const float* __restrict__ out_part,
                                              const float* __restrict__ bias_g,
                                              float* __restrict__ out) {
    int t = threadIdx.x, b = blockIdx.x;
    float acc = 0.f;
    #pragma unroll
    for (int k = 0; k < 32; k++) acc += out_part[((size_t)k * 64 + b) * 256 + t];
    out[b * 256 + t] = bias_g[t] + acc * (1.f / 4096.f);
}

extern "C" void kernel_launch(void* const* d_in, const int* in_sizes, int n_in,
                              void* d_out, int out_size, void* d_ws, size_t ws_size,
                              hipStream_t stream) {
    const float* x       = (const float*)d_in[0];
    const float* W1      = (const float*)d_in[1];
    const float* b1      = (const float*)d_in[2];
    const float* Wg      = (const float*)d_in[3];
    const float* att_src = (const float*)d_in[4];
    const float* att_dst = (const float*)d_in[5];
    const float* bias_g  = (const float*)d_in[6];
    float* out = (float*)d_out;

    float* ws       = (float*)d_ws;
    float* was      = ws;                         // 2048
    float* wad      = ws + 2048;                  // 2048
    float* c_sd     = ws + 4096;                  // 16
    ushort* Bpk     = (ushort*)(ws + 4112);       // 24576 u16 = 12288 f
    float* a_src    = ws + 16400;                 // 262144
    float* a_dst    = ws + 278544;                // 262144
    float* wsum     = ws + 540688;                // 262144
    float* s_w      = ws + 802832;                // 512
    float* z_part   = ws + 803344;                // 3145728
    float* y_part   = ws + 3949072;               // 524288
    float* out_part = ws + 4473360;               // 524288  -> total ~20.0 MB

    k_att_proj<<<dim3(HEADS, 2), 256, 0, stream>>>(Wg, att_src, att_dst, was, wad);
    k_prep_was1<<<24, 256, 0, stream>>>(W1, b1, was, wad, Bpk, c_sd);
    k_logits<<<M_ROWS / 64, 256, 0, stream>>>(x, Bpk, c_sd, a_src, a_dst);
    k_softmax<<<BATCH * HEADS, 512, 0, stream>>>(a_src, a_dst, wsum, s_w);
    k_zsum<<<dim3(BATCH, 8), 256, 0, stream>>>(wsum, x, z_part);
    k_y<<<dim3(BATCH, 4), 256, 0, stream>>>(z_part, W1, b1, s_w, y_part);
    k_out<<<dim3(HEADS, 4, 4), 256, 0, stream>>>(y_part, Wg, out_part);
    k_out2<<<BATCH, 256, 0, stream>>>(out_part, bias_g, out);
}

// Round 6
// 100.371 us; speedup vs baseline: 3.5316x; 1.0395x over previous
//
#include <hip/hip_runtime.h>

#define BATCH 64
#define NNODE 512
#define D_IN 768
#define FEA 256
#define HEADS 8
#define M_ROWS (BATCH * NNODE)   // 32768
#define NEG_SLOPE 0.2f
#define LOG2E 1.4426950408889634f

typedef __attribute__((ext_vector_type(4))) float f32x4;
typedef __attribute__((ext_vector_type(8))) short bf16x8;

__device__ __forceinline__ ushort f2bf(float f) {
    union { float f; unsigned u; } v; v.f = f;
    unsigned r = v.u + 0x7fffu + ((v.u >> 16) & 1u);   // RNE
    return (ushort)(r >> 16);
}
__device__ __forceinline__ float exp2fast(float v) { return __builtin_amdgcn_exp2f(v); }

// P0: fold attention vectors into Wg: was[h][f] = sum_c Wg[f, h*FEA+c] * att[h,c]
__global__ __launch_bounds__(256) void k_att_proj(const float* __restrict__ Wg,
                                                  const float* __restrict__ att_src,
                                                  const float* __restrict__ att_dst,
                                                  float* __restrict__ was,
                                                  float* __restrict__ wad) {
    int h = blockIdx.x;
    int f = threadIdx.x;
    const float* a = (blockIdx.y == 0) ? att_src : att_dst;
    float* o = (blockIdx.y == 0) ? was : wad;
    const float* wrow = Wg + (size_t)f * (HEADS * FEA) + h * FEA;
    const float* av = a + h * FEA;
    float acc = 0.f;
    #pragma unroll 4
    for (int c = 0; c < FEA; c++) acc += wrow[c] * av[c];
    o[h * FEA + f] = acc;
}

// P1: Was1[d,col] = sum_f W1[d,f]*wv[col,f] packed bf16 in MFMA B-frag layout; c_sd = b1.wv
__global__ __launch_bounds__(256) void k_prep_was1(const float* __restrict__ W1,
                                                   const float* __restrict__ b1,
                                                   const float* __restrict__ was,
                                                   const float* __restrict__ wad,
                                                   ushort* __restrict__ Bpk,
                                                   float* __restrict__ c_sd) {
    __shared__ float wvl[16 * 260];
    int t = threadIdx.x;
    int kt = blockIdx.x;
    for (int sIdx = t; sIdx < 4096; sIdx += 256) {
        int col = sIdx >> 8, f = sIdx & 255;
        wvl[col * 260 + f] = (col < 8) ? was[col * 256 + f] : wad[(col - 8) * 256 + f];
    }
    __syncthreads();
    int kl = t >> 4, col = t & 15;
    #pragma unroll
    for (int half = 0; half < 2; half++) {
        int kloc = kl + half * 16;
        int k = kt * 32 + kloc;
        const float* wrow = W1 + (size_t)k * 256;
        float acc = 0.f;
        #pragma unroll 4
        for (int f0 = 0; f0 < 256; f0 += 4) {
            float4 a4 = *(const float4*)&wrow[f0];
            float4 v4 = *(const float4*)&wvl[col * 260 + f0];
            acc += a4.x * v4.x + a4.y * v4.y + a4.z * v4.z + a4.w * v4.w;
        }
        Bpk[kt * 1024 + ((kloc >> 3) * 16 + col) * 8 + (kloc & 7)] = f2bf(acc);
    }
    if (kt == 0 && t < 16) {
        float a = 0.f;
        for (int f = 0; f < 256; f++) a += b1[f] * wvl[t * 260 + f];
        c_sd[t] = a;
    }
}

// K1: logits = (x @ Was1 + c_sd) * LOG2E via one MFMA column per wave; depth-3 reg pipeline
__global__ __launch_bounds__(256) void k_logits(const float* __restrict__ x,
                                                const ushort* __restrict__ Bpk,
                                                const float* __restrict__ c_sd,
                                                float* __restrict__ a_src,
                                                float* __restrict__ a_dst) {
    int t = threadIdx.x;
    int w = t >> 6, l = t & 63;
    int lr = l & 15, lk = l >> 4;
    int row0w = blockIdx.x * 64 + w * 16;
    const float* ap = x + (size_t)(row0w + lr) * D_IN + lk * 8;
    const ushort* bp = Bpk + l * 8;

    f32x4 A0[3], A1[3];
    bf16x8 Bf[3];
    A0[0] = *(const f32x4*)(ap);      A1[0] = *(const f32x4*)(ap + 4);
    Bf[0] = *(const bf16x8*)(bp);
    A0[1] = *(const f32x4*)(ap + 32); A1[1] = *(const f32x4*)(ap + 36);
    Bf[1] = *(const bf16x8*)(bp + 1024);
    f32x4 acc = {};

    #pragma unroll
    for (int kt = 0; kt < 24; kt++) {
        int cur = kt % 3;
        if (kt + 2 < 24) {
            int nx = (kt + 2) % 3;
            A0[nx] = *(const f32x4*)(ap + (kt + 2) * 32);
            A1[nx] = *(const f32x4*)(ap + (kt + 2) * 32 + 4);
            Bf[nx] = *(const bf16x8*)(bp + (size_t)(kt + 2) * 1024);
        }
        bf16x8 af;
        af[0] = (short)f2bf(A0[cur].x); af[1] = (short)f2bf(A0[cur].y);
        af[2] = (short)f2bf(A0[cur].z); af[3] = (short)f2bf(A0[cur].w);
        af[4] = (short)f2bf(A1[cur].x); af[5] = (short)f2bf(A1[cur].y);
        af[6] = (short)f2bf(A1[cur].z); af[7] = (short)f2bf(A1[cur].w);
        acc = __builtin_amdgcn_mfma_f32_16x16x32_bf16(af, Bf[cur], acc, 0, 0, 0);
    }
    int col = lr;
    float cadd = c_sd[col];
    float* dst = (col < 8) ? a_src : a_dst;
    int h = col & 7;
    #pragma unroll
    for (int r = 0; r < 4; r++) {
        int rr = row0w + lk * 4 + r;
        int b = rr >> 9, n = rr & 511;
        dst[((size_t)(b * 8 + h) << 9) + n] = (acc[r] + cadd) * LOG2E;
    }
}

// K2: O(N log N) softmax column-sums via sort + prefix sums — barrier-minimal version.
// In-wave bitonic stages via shfl_xor (no barrier); only j>=64 through LDS.
__global__ __launch_bounds__(512) void k_softmax(const float* __restrict__ a_src,
                                                 const float* __restrict__ a_dst,
                                                 float* __restrict__ wout,
                                                 float* __restrict__ s_w) {
    __shared__ float s_srt[512], d_srt[512];
    __shared__ float E1[512], E2[512], PA[512], PB[512];
    __shared__ float red[8], tA[8], tB[8];
    int t = threadIdx.x;
    int lane = t & 63, wv = t >> 6;
    int bh = blockIdx.x;
    float sv = a_src[((size_t)bh << 9) + t];
    float dv = a_dst[((size_t)bh << 9) + t];
    float v_s = sv, v_d = dv;
    // smax over s
    float mx = sv;
    #pragma unroll
    for (int off = 32; off; off >>= 1) mx = fmaxf(mx, __shfl_xor(mx, off));
    if (lane == 0) red[wv] = mx;
    __syncthreads();
    mx = red[0];
    #pragma unroll
    for (int k = 1; k < 8; k++) mx = fmaxf(mx, red[k]);
    // bitonic sort ascending of v_s and v_d (independent networks, shared structure)
    for (int k = 2; k <= 512; k <<= 1) {
        for (int j = k >> 1; j > 0; j >>= 1) {
            bool lower = ((t & j) == 0);
            bool tmin = (lower == ((t & k) == 0));
            if (j >= 64) {
                __syncthreads();
                s_srt[t] = v_s; d_srt[t] = v_d;
                __syncthreads();
                float ps = s_srt[t ^ j], pd = d_srt[t ^ j];
                v_s = tmin ? fminf(v_s, ps) : fmaxf(v_s, ps);
                v_d = tmin ? fminf(v_d, pd) : fmaxf(v_d, pd);
            } else {
                float ps = __shfl_xor(v_s, j);
                float pd = __shfl_xor(v_d, j);
                v_s = tmin ? fminf(v_s, ps) : fmaxf(v_s, ps);
                v_d = tmin ? fminf(v_d, pd) : fmaxf(v_d, pd);
            }
        }
    }
    __syncthreads();
    s_srt[t] = v_s; d_srt[t] = v_d;
    // E1/E2 inclusive prefix over sorted s: in-wave shfl scan + cross-wave totals
    float e1 = exp2fast(v_s - mx);
    float e2 = exp2fast(0.2f * (v_s - mx));
    #pragma unroll
    for (int off = 1; off < 64; off <<= 1) {
        float u1 = __shfl_up(e1, off);
        float u2 = __shfl_up(e2, off);
        if (lane >= off) { e1 += u1; e2 += u2; }
    }
    if (lane == 63) { tA[wv] = e1; tB[wv] = e2; }
    __syncthreads();
    float pre1 = 0.f, pre2 = 0.f, tot1 = 0.f, tot2 = 0.f;
    #pragma unroll
    for (int k = 0; k < 8; k++) {
        float a = tA[k], b = tB[k];
        tot1 += a; tot2 += b;
        if (k < wv) { pre1 += a; pre2 += b; }
    }
    e1 += pre1; e2 += pre2;
    E1[t] = e1; E2[t] = e2;
    __syncthreads();
    // per sorted-row: L_i and normalized pieces
    float v = v_d + mx;
    float mi = fmaxf(v, NEG_SLOPE * v);
    float key = -v_d;
    int lo = 0, hi = 512;
    #pragma unroll
    for (int it = 0; it < 9; it++) {
        if (lo < hi) {
            int mid = (lo + hi) >> 1;
            if (s_srt[mid] < key) lo = mid + 1; else hi = mid;
        }
    }
    float e1pre = lo ? E1[lo - 1] : 0.f;
    float e2pre = lo ? E2[lo - 1] : 0.f;
    float ga = exp2fast(v - mi);
    float gb = exp2fast(0.2f * v - mi);
    float L = ga * (tot1 - e1pre) + gb * e2pre;
    float linv = 1.f / L;
    float pa = ga * linv, pb = gb * linv;
    // PA/PB inclusive prefix over sorted-d rows
    #pragma unroll
    for (int off = 1; off < 64; off <<= 1) {
        float u1 = __shfl_up(pa, off);
        float u2 = __shfl_up(pb, off);
        if (lane >= off) { pa += u1; pb += u2; }
    }
    __syncthreads();   // tA/tB reuse
    if (lane == 63) { tA[wv] = pa; tB[wv] = pb; }
    __syncthreads();
    float prp1 = 0.f, prp2 = 0.f, totp1 = 0.f, totp2 = 0.f;
    #pragma unroll
    for (int k = 0; k < 8; k++) {
        float a = tA[k], b = tB[k];
        totp1 += a; totp2 += b;
        if (k < wv) { prp1 += a; prp2 += b; }
    }
    pa += prp1; pb += prp2;
    PA[t] = pa; PB[t] = pb;
    __syncthreads();
    // per original column j = t
    float key2 = -sv;
    int lo2 = 0, hi2 = 512;
    #pragma unroll
    for (int it = 0; it < 9; it++) {
        if (lo2 < hi2) {
            int mid = (lo2 + hi2) >> 1;
            if (d_srt[mid] < key2) lo2 = mid + 1; else hi2 = mid;
        }
    }
    float papre = lo2 ? PA[lo2 - 1] : 0.f;
    float pbpre = lo2 ? PB[lo2 - 1] : 0.f;
    float e1j = exp2fast(sv - mx);
    float e2j = exp2fast(0.2f * (sv - mx));
    float wj = e1j * (totp1 - papre) + e2j * pbpre;
    wout[((size_t)bh << 9) + t] = wj;
    // s_w reduce
    float ssum = wj;
    #pragma unroll
    for (int off = 32; off; off >>= 1) ssum += __shfl_xor(ssum, off);
    __syncthreads();
    if (lane == 0) red[wv] = ssum;
    __syncthreads();
    if (t == 0) {
        float a = 0.f;
        #pragma unroll
        for (int k = 0; k < 8; k++) a += red[k];
        s_w[bh] = a;
    }
}

// K3: z_part[(b*8+jc)*8+h][d] = sum_{j in chunk} w[b,h,j] * x[b,j,d]
__global__ __launch_bounds__(256) void k_zsum(const float* __restrict__ w,
                                              const float* __restrict__ x,
                                              float* __restrict__ z_part) {
    __shared__ float wl[512];   // [h][64]
    int t = threadIdx.x;
    int b = blockIdx.x, jc = blockIdx.y;
    {
        int idx = t;
        wl[idx] = w[((size_t)(b * 8 + (idx >> 6)) << 9) + jc * 64 + (idx & 63)];
        idx = t + 256;
        wl[idx] = w[((size_t)(b * 8 + (idx >> 6)) << 9) + jc * 64 + (idx & 63)];
    }
    __syncthreads();
    float acc[8][3] = {};
    const float* xp = x + ((size_t)(b * 512 + jc * 64)) * D_IN + t;
    for (int j0 = 0; j0 < 64; j0 += 4) {
        float4 wq[8];
        #pragma unroll
        for (int h = 0; h < 8; h++) wq[h] = *(const float4*)&wl[h * 64 + j0];
        #pragma unroll
        for (int jj = 0; jj < 4; jj++) {
            float x0 = xp[(size_t)(j0 + jj) * D_IN];
            float x1 = xp[(size_t)(j0 + jj) * D_IN + 256];
            float x2 = xp[(size_t)(j0 + jj) * D_IN + 512];
            #pragma unroll
            for (int h = 0; h < 8; h++) {
                float wv = (jj == 0) ? wq[h].x : (jj == 1) ? wq[h].y : (jj == 2) ? wq[h].z : wq[h].w;
                acc[h][0] += wv * x0;
                acc[h][1] += wv * x1;
                acc[h][2] += wv * x2;
            }
        }
    }
    #pragma unroll
    for (int h = 0; h < 8; h++) {
        size_t base = ((size_t)((b * 8 + jc) * 8 + h)) * D_IN + t;
        z_part[base] = acc[h][0];
        z_part[base + 256] = acc[h][1];
        z_part[base + 512] = acc[h][2];
    }
}

// K4: y_part[ds][bh][f] = sum_{d in slice} z[bh,d]*W1[d,f]  (+ s_w*b1 on ds==0)
__global__ __launch_bounds__(256) void k_y(const float* __restrict__ z_part,
                                           const float* __restrict__ W1,
                                           const float* __restrict__ b1,
                                           const float* __restrict__ s_w,
                                           float* __restrict__ y_part) {
    __shared__ float zl[8 * 196];
    int t = threadIdx.x;
    int b = blockIdx.x, ds = blockIdx.y;
    for (int sIdx = t; sIdx < 1536; sIdx += 256) {
        int k = sIdx / 192, dd = sIdx - k * 192;
        float v = 0.f;
        #pragma unroll
        for (int jc = 0; jc < 8; jc++)
            v += z_part[((size_t)((b * 8 + jc) * 8 + k)) * D_IN + ds * 192 + dd];
        zl[k * 196 + dd] = v;
    }
    __syncthreads();
    float acc[8] = {};
    for (int dq = 0; dq < 48; dq++) {
        int dbase = ds * 192 + dq * 4;
        float w0 = W1[(size_t)(dbase + 0) * 256 + t];
        float w1 = W1[(size_t)(dbase + 1) * 256 + t];
        float w2 = W1[(size_t)(dbase + 2) * 256 + t];
        float w3 = W1[(size_t)(dbase + 3) * 256 + t];
        #pragma unroll
        for (int k = 0; k < 8; k++) {
            float4 zq = *(const float4*)&zl[k * 196 + dq * 4];
            acc[k] += zq.x * w0 + zq.y * w1 + zq.z * w2 + zq.w * w3;
        }
    }
    #pragma unroll
    for (int k = 0; k < 8; k++) {
        float v = acc[k];
        if (ds == 0) v += s_w[b * 8 + k] * b1[t];
        y_part[((size_t)ds * 512 + b * 8 + k) * 256 + t] = v;
    }
}

// K5: out_part[(h*4+fs)][b][c] = sum_{f in fs-slice} Y[b,h,f]*Wg[f, h*256+c]
__global__ __launch_bounds__(256) void k_out(const float* __restrict__ y_part,
                                             const float* __restrict__ Wg,
                                             float* __restrict__ out_part) {
    __shared__ float Yl[64][16];   // [fl][bl]
    int t = threadIdx.x;
    int h = blockIdx.x, fs = blockIdx.y, bq = blockIdx.z;
    int f0 = fs * 64, b0 = bq * 16;
    for (int sIdx = t; sIdx < 1024; sIdx += 256) {
        int bl = sIdx >> 6, fl = sIdx & 63;
        float v = 0.f;
        #pragma unroll
        for (int ds = 0; ds < 4; ds++)
            v += y_part[((size_t)(ds * 512) + (b0 + bl) * 8 + h) * 256 + f0 + fl];
        Yl[fl][bl] = v;
    }
    __syncthreads();
    float acc[16] = {};
    for (int fl = 0; fl < 64; fl++) {
        float wv = Wg[(size_t)(f0 + fl) * 2048 + h * 256 + t];
        #pragma unroll
        for (int bl = 0; bl < 16; bl++) acc[bl] += Yl[fl][bl] * wv;
    }
    #pragma unroll
    for (int bl = 0; bl < 16; bl++)
        out_part[((size_t)(h * 4 + fs) * 64 + b0 + bl) * 256 + t] = acc[bl];
}

// K6: out[b,c] = bias_g[c] + (1/4096) * sum_k out_part[k][b][c]
__global__ __launch_bounds__(256) void k_out2(const float* __restrict__ out_part,
                                              const float* __restrict__ bias_g,
                                              float* __restrict__ out) {
    int t = threadIdx.x, b = blockIdx.x;
    float acc = 0.f;
    #pragma unroll
    for (int k = 0; k < 32; k++) acc += out_part[((size_t)k * 64 + b) * 256 + t];
    out[b * 256 + t] = bias_g[t] + acc * (1.f / 4096.f);
}

extern "C" void kernel_launch(void* const* d_in, const int* in_sizes, int n_in,
                              void* d_out, int out_size, void* d_ws, size_t ws_size,
                              hipStream_t stream) {
    const float* x       = (const float*)d_in[0];
    const float* W1      = (const float*)d_in[1];
    const float* b1      = (const float*)d_in[2];
    const float* Wg      = (const float*)d_in[3];
    const float* att_src = (const float*)d_in[4];
    const float* att_dst = (const float*)d_in[5];
    const float* bias_g  = (const float*)d_in[6];
    float* out = (float*)d_out;

    float* ws       = (float*)d_ws;
    float* was      = ws;                         // 2048
    float* wad      = ws + 2048;                  // 2048
    float* c_sd     = ws + 4096;                  // 16
    ushort* Bpk     = (ushort*)(ws + 4112);       // 24576 u16 = 12288 f
    float* a_src    = ws + 16400;                 // 262144
    float* a_dst    = ws + 278544;                // 262144
    float* wsum     = ws + 540688;                // 262144
    float* s_w      = ws + 802832;                // 512
    float* z_part   = ws + 803344;                // 3145728
    float* y_part   = ws + 3949072;               // 524288
    float* out_part = ws + 4473360;               // 524288  -> total ~20.0 MB

    k_att_proj<<<dim3(HEADS, 2), 256, 0, stream>>>(Wg, att_src, att_dst, was, wad);
    k_prep_was1<<<24, 256, 0, stream>>>(W1, b1, was, wad, Bpk, c_sd);
    k_logits<<<M_ROWS / 64, 256, 0, stream>>>(x, Bpk, c_sd, a_src, a_dst);
    k_softmax<<<BATCH * HEADS, 512, 0, stream>>>(a_src, a_dst, wsum, s_w);
    k_zsum<<<dim3(BATCH, 8), 256, 0, stream>>>(wsum, x, z_part);
    k_y<<<dim3(BATCH, 4), 256, 0, stream>>>(z_part, W1, b1, s_w, y_part);
    k_out<<<dim3(HEADS, 4, 4), 256, 0, stream>>>(y_part, Wg, out_part);
    k_out2<<<BATCH, 256, 0, stream>>>(out_part, bias_g, out);
}